// Round 1
// baseline (255.822 us; speedup 1.0000x reference)
//
#include <hip/hip_runtime.h>

#define NB 32
#define NC 256
#define NH 64
#define NW 64
#define NK 16
#define HW (NH * NW)  // 4096

__device__ __forceinline__ float fsig(float z) {
    // sigmoid(z) = 1/(1+exp(-z)); fast exp + hw rcp (plenty accurate vs 5.9e-2 threshold)
    return __builtin_amdgcn_rcpf(1.0f + __expf(-z));
}

__global__ __launch_bounds__(256, 4) void pse_kernel(
    const float* __restrict__ x,
    const float* __restrict__ w1,
    const float* __restrict__ b1,
    const float* __restrict__ w2,
    const float* __restrict__ b2,
    float* __restrict__ out)
{
    __shared__ float  w2t[NK][NC];     // 16 KiB: w2 transposed -> w2t[k][c]
    __shared__ float4 part[16][17];    // padded partial channel-sums [cg][q]
    __shared__ float4 hv4[NK][16];     // hv[k][q]: relu MLP hidden, float4 over w
    __shared__ float4 s4[16];          // per-quad channel means

    const int t  = threadIdx.x;
    const int cg = t >> 4;   // 0..15 : which 16-channel group
    const int q  = t & 15;   // 0..15 : which w-quad (float4)

    const int bh = blockIdx.x;      // 0..2047
    const int b  = bh >> 6;
    const int h  = bh & 63;

    // x[b, c, h, w] = x[ b*NC*HW + c*HW + h*NW + w ]
    const size_t base = (size_t)b * NC * HW + (size_t)h * NW;
    const float* __restrict__ xp = x + base;
    float* __restrict__ op       = out + base;

    // ---- stage w2 transposed into LDS (4096 floats = 1024 float4; 4 per thread)
    {
        const float4* w2v = reinterpret_cast<const float4*>(w2);
        #pragma unroll
        for (int r = 0; r < 4; ++r) {
            const int idx = t + (r << 8);          // 0..1023
            const float4 v = w2v[idx];
            const int c  = idx >> 2;               // channel
            const int k0 = (idx & 3) << 2;         // k base
            w2t[k0 + 0][c] = v.x;
            w2t[k0 + 1][c] = v.y;
            w2t[k0 + 2][c] = v.z;
            w2t[k0 + 3][c] = v.w;
        }
    }

    // ---- phase 1: coalesced read of this (b,h) slice, partial sums over 16 channels
    {
        const float* xr = xp + (size_t)(cg << 4) * HW + (q << 2);
        float4 pacc = make_float4(0.f, 0.f, 0.f, 0.f);
        #pragma unroll
        for (int i = 0; i < 16; ++i) {
            const float4 v = *reinterpret_cast<const float4*>(xr + (size_t)i * HW);
            pacc.x += v.x; pacc.y += v.y; pacc.z += v.z; pacc.w += v.w;
        }
        part[cg][q] = pacc;
    }
    __syncthreads();

    // ---- phase 2a: final channel mean s[w] (16 threads, one per w-quad)
    if (t < 16) {
        float4 s = make_float4(0.f, 0.f, 0.f, 0.f);
        #pragma unroll
        for (int i = 0; i < 16; ++i) {
            const float4 v = part[i][t];
            s.x += v.x; s.y += v.y; s.z += v.z; s.w += v.w;
        }
        const float inv = 1.0f / (float)NC;
        s.x *= inv; s.y *= inv; s.z *= inv; s.w *= inv;
        s4[t] = s;
    }
    __syncthreads();

    // ---- phase 2b: hidden layer hv[k][w] = relu(s*w1k + b1k); thread t -> (k=cg, q)
    {
        const float4 s  = s4[q];
        const float w1k = w1[cg];
        const float b1k = b1[cg];
        float4 hvv;
        hvv.x = fmaxf(fmaf(s.x, w1k, b1k), 0.f);
        hvv.y = fmaxf(fmaf(s.y, w1k, b1k), 0.f);
        hvv.z = fmaxf(fmaf(s.z, w1k, b1k), 0.f);
        hvv.w = fmaxf(fmaf(s.w, w1k, b1k), 0.f);
        hv4[cg][q] = hvv;
    }
    __syncthreads();

    // ---- phase 3: logits for 16 channels x float4 of w
    float4 acc[16];
    #pragma unroll
    for (int i = 0; i < 16; ++i) {
        const float bb = b2[(cg << 4) + i];
        acc[i] = make_float4(bb, bb, bb, bb);
    }

    #pragma unroll
    for (int k = 0; k < NK; ++k) {
        const float4 hk = hv4[k][q];
        const float4* wr = reinterpret_cast<const float4*>(&w2t[k][cg << 4]);
        const float4 wa = wr[0], wb = wr[1], wc = wr[2], wd = wr[3];
        const float wv[16] = {wa.x, wa.y, wa.z, wa.w, wb.x, wb.y, wb.z, wb.w,
                              wc.x, wc.y, wc.z, wc.w, wd.x, wd.y, wd.z, wd.w};
        #pragma unroll
        for (int i = 0; i < 16; ++i) {
            acc[i].x = fmaf(hk.x, wv[i], acc[i].x);
            acc[i].y = fmaf(hk.y, wv[i], acc[i].y);
            acc[i].z = fmaf(hk.z, wv[i], acc[i].z);
            acc[i].w = fmaf(hk.w, wv[i], acc[i].w);
        }
    }

    // ---- epilogue: re-read x (L2/L3-resident), apply sigmoid gate, coalesced store
    #pragma unroll
    for (int i = 0; i < 16; ++i) {
        const size_t off = (size_t)((cg << 4) + i) * HW + (q << 2);
        const float4 xv = *reinterpret_cast<const float4*>(xp + off);
        const float4 a  = acc[i];
        float4 r;
        r.x = xv.x * fsig(a.x);
        r.y = xv.y * fsig(a.y);
        r.z = xv.z * fsig(a.z);
        r.w = xv.w * fsig(a.w);
        *reinterpret_cast<float4*>(op + off) = r;
    }
}

extern "C" void kernel_launch(void* const* d_in, const int* in_sizes, int n_in,
                              void* d_out, int out_size, void* d_ws, size_t ws_size,
                              hipStream_t stream) {
    const float* x  = (const float*)d_in[0];
    const float* w1 = (const float*)d_in[1];
    const float* b1 = (const float*)d_in[2];
    const float* w2 = (const float*)d_in[3];
    const float* b2 = (const float*)d_in[4];
    float* out = (float*)d_out;

    dim3 grid(NB * NH);   // 2048 blocks: one per (b, h) row
    dim3 block(256);
    hipLaunchKernelGGL(pse_kernel, grid, block, 0, stream, x, w1, b1, w2, b2, out);
}

// Round 3
// 237.743 us; speedup vs baseline: 1.0760x; 1.0760x over previous
//
#include <hip/hip_runtime.h>

#define NB 32
#define NC 256
#define NH 64
#define NW 64
#define NK 16
#define HW (NH * NW)  // 4096

typedef float f32x4 __attribute__((ext_vector_type(4)));  // native vec for nontemporal builtins

__device__ __forceinline__ float fsig(float z) {
    // sigmoid(z) = 1/(1+exp(-z)); fast exp + hw rcp (vs 5.9e-2 threshold: plenty)
    return __builtin_amdgcn_rcpf(1.0f + __expf(-z));
}

__global__ __launch_bounds__(256, 4) void pse_kernel(
    const float* __restrict__ x,
    const float* __restrict__ w1,
    const float* __restrict__ b1,
    const float* __restrict__ w2,
    const float* __restrict__ b2,
    float* __restrict__ out)
{
    // w2t stride NC+4=260: breaks the 4-way bank conflict on staging writes
    // while keeping 16B alignment for float4 reads.
    __shared__ float w2t[NK][NC + 4];   // 16.6 KiB, w2 transposed -> w2t[k][c]
    __shared__ f32x4 part[16][17];      // partial channel-sums [cg][q], padded
    __shared__ f32x4 hv4[NK][16];       // hidden layer hv[k][q]
    __shared__ f32x4 s4[16];            // per-quad channel means
    __shared__ float b2s[NC];           // bias2 staged

    const int t  = threadIdx.x;
    const int cg = t >> 4;   // 0..15 : 16-channel group
    const int q  = t & 15;   // 0..15 : w-quad (float4)

    const int bh = blockIdx.x;   // 0..2047
    const int b  = bh >> 6;
    const int h  = bh & 63;

    const size_t base = (size_t)b * NC * HW + (size_t)h * NW;
    const float* __restrict__ xp = x + base;
    float* __restrict__ op       = out + base;
    const float* __restrict__ xr = xp + (size_t)(cg << 4) * HW + (q << 2);

    // ---- issue ALL 16 x loads first; keep register-resident (forces 16 in flight)
    f32x4 xv[16];
    #pragma unroll
    for (int i = 0; i < 16; ++i)
        xv[i] = __builtin_nontemporal_load(
            reinterpret_cast<const f32x4*>(xr + (size_t)i * HW));

    // ---- stage w2 (transposed) + b2 into LDS while x loads are in flight
    {
        const f32x4* __restrict__ w2v = reinterpret_cast<const f32x4*>(w2);
        #pragma unroll
        for (int r = 0; r < 4; ++r) {
            const int idx = t + (r << 8);          // 0..1023
            const f32x4 v = w2v[idx];
            const int c  = idx >> 2;               // channel
            const int k0 = (idx & 3) << 2;         // k base
            w2t[k0 + 0][c] = v.x;
            w2t[k0 + 1][c] = v.y;
            w2t[k0 + 2][c] = v.z;
            w2t[k0 + 3][c] = v.w;
        }
        b2s[t] = b2[t];
    }

    // ---- partial channel sums over this thread's 16 channels
    {
        f32x4 p = (f32x4)(0.f);
        #pragma unroll
        for (int i = 0; i < 16; ++i) p += xv[i];
        part[cg][q] = p;
    }
    __syncthreads();

    // ---- final channel mean s[w] (16 threads, one per w-quad)
    if (t < 16) {
        f32x4 s = (f32x4)(0.f);
        #pragma unroll
        for (int i = 0; i < 16; ++i) s += part[i][t];
        s *= (1.0f / (float)NC);
        s4[t] = s;
    }
    __syncthreads();

    // ---- hidden layer hv[k][w] = relu(s*w1k + b1k); thread t -> (k=cg, q)
    {
        const f32x4 s  = s4[q];
        const float w1k = w1[cg];
        const float b1k = b1[cg];
        f32x4 hvv;
        hvv.x = fmaxf(fmaf(s.x, w1k, b1k), 0.f);
        hvv.y = fmaxf(fmaf(s.y, w1k, b1k), 0.f);
        hvv.z = fmaxf(fmaf(s.z, w1k, b1k), 0.f);
        hvv.w = fmaxf(fmaf(s.w, w1k, b1k), 0.f);
        hv4[cg][q] = hvv;
    }
    __syncthreads();

    // ---- logits + gate + store, in two 8-channel halves (keeps VGPR <= ~120)
    #pragma unroll
    for (int half = 0; half < 2; ++half) {
        const int c0 = (cg << 4) + (half << 3);

        f32x4 acc[8];
        #pragma unroll
        for (int j = 0; j < 8; ++j) acc[j] = (f32x4)(b2s[c0 + j]);

        #pragma unroll
        for (int k = 0; k < NK; ++k) {
            const f32x4 hk = hv4[k][q];
            const f32x4* __restrict__ wr =
                reinterpret_cast<const f32x4*>(&w2t[k][c0]);
            const f32x4 wa = wr[0], wb = wr[1];
            const float wv[8] = {wa.x, wa.y, wa.z, wa.w, wb.x, wb.y, wb.z, wb.w};
            #pragma unroll
            for (int j = 0; j < 8; ++j) {
                acc[j].x = fmaf(hk.x, wv[j], acc[j].x);
                acc[j].y = fmaf(hk.y, wv[j], acc[j].y);
                acc[j].z = fmaf(hk.z, wv[j], acc[j].z);
                acc[j].w = fmaf(hk.w, wv[j], acc[j].w);
            }
        }

        #pragma unroll
        for (int j = 0; j < 8; ++j) {
            const int i = (half << 3) + j;
            const f32x4 xvv = xv[i];
            f32x4 r;
            r.x = xvv.x * fsig(acc[j].x);
            r.y = xvv.y * fsig(acc[j].y);
            r.z = xvv.z * fsig(acc[j].z);
            r.w = xvv.w * fsig(acc[j].w);
            __builtin_nontemporal_store(r,
                reinterpret_cast<f32x4*>(op + (size_t)(c0 + j) * HW + (q << 2)));
        }
    }
}

extern "C" void kernel_launch(void* const* d_in, const int* in_sizes, int n_in,
                              void* d_out, int out_size, void* d_ws, size_t ws_size,
                              hipStream_t stream) {
    const float* x  = (const float*)d_in[0];
    const float* w1 = (const float*)d_in[1];
    const float* b1 = (const float*)d_in[2];
    const float* w2 = (const float*)d_in[3];
    const float* b2 = (const float*)d_in[4];
    float* out = (float*)d_out;

    dim3 grid(NB * NH);   // 2048 blocks: one per (b, h) row
    dim3 block(256);
    hipLaunchKernelGGL(pse_kernel, grid, block, 0, stream, x, w1, b1, w2, b2, out);
}

// Round 4
// 228.814 us; speedup vs baseline: 1.1180x; 1.0390x over previous
//
#include <hip/hip_runtime.h>

#define NB 32
#define NC 256
#define NH 64
#define NW 64
#define NK 16
#define HW (NH * NW)  // 4096

typedef float f32x4 __attribute__((ext_vector_type(4)));

__device__ __forceinline__ float fsig(float z) {
    // sigmoid(z) = 1/(1+exp(-z)); fast exp + hw rcp (vs 5.9e-2 threshold: plenty)
    return __builtin_amdgcn_rcpf(1.0f + __expf(-z));
}

// 1024 threads per (b,h) slice: thread (cg = t>>4 in 0..63, q = t&15) owns
// channels 4cg..4cg+3 x w-quad q. xv[4]=16 VGPR keeps total <=64 so
// __launch_bounds__(1024,8) gives 2 blocks/CU = 32 waves/CU (full occupancy):
// blocks in different phases (load/reduce/store) interleave on the memory pipe.
__global__ __launch_bounds__(1024, 8) void pse_kernel(
    const float* __restrict__ x,
    const float* __restrict__ w1,
    const float* __restrict__ b1,
    const float* __restrict__ w2,
    const float* __restrict__ b2,
    float* __restrict__ out)
{
    __shared__ float w2t[NK][NC + 4];  // 16.6 KiB, w2 transposed -> w2t[k][c]
    __shared__ f32x4 part[64][17];     // 17.4 KiB, per-thread partial sums [cg][q]
    __shared__ f32x4 sA[16][17];       //  4.4 KiB, stage-A reduced sums [a][q]
    __shared__ f32x4 hv4[NK][16];      //  4.0 KiB, hidden layer hv[k][q]
    __shared__ float b2s[NC];          //  1.0 KiB

    const int t  = threadIdx.x;
    const int cg = t >> 4;   // 0..63 : 4-channel group
    const int q  = t & 15;   // 0..15 : w-quad

    const int bh = blockIdx.x;   // 0..2047
    const int b  = bh >> 6;
    const int h  = bh & 63;

    const size_t base = (size_t)b * NC * HW + (size_t)h * NW;
    const float* __restrict__ xp = x + base;
    float* __restrict__ op       = out + base;
    const float* __restrict__ xr = xp + (size_t)(cg << 2) * HW + (q << 2);

    // ---- 4 x-loads, register-resident until the gated store
    f32x4 xv[4];
    #pragma unroll
    for (int i = 0; i < 4; ++i)
        xv[i] = __builtin_nontemporal_load(
            reinterpret_cast<const f32x4*>(xr + (size_t)i * HW));

    // ---- stage w2 transposed + b2 while x loads are in flight
    {
        const f32x4 v = reinterpret_cast<const f32x4*>(w2)[t];  // 1024 float4, 1/thread
        const int c  = t >> 2;          // channel
        const int k0 = (t & 3) << 2;    // k base
        w2t[k0 + 0][c] = v.x;
        w2t[k0 + 1][c] = v.y;
        w2t[k0 + 2][c] = v.z;
        w2t[k0 + 3][c] = v.w;
        if (t < NC) b2s[t] = b2[t];
    }

    // ---- per-thread partial channel sum (4 channels)
    part[cg][q] = xv[0] + xv[1] + xv[2] + xv[3];
    __syncthreads();

    // ---- stage A: 256 threads fold 64 partials -> 16 per quad
    if (t < 256) {
        const int a = t >> 4;   // 0..15
        sA[a][q] = part[4 * a + 0][q] + part[4 * a + 1][q]
                 + part[4 * a + 2][q] + part[4 * a + 3][q];
    }
    __syncthreads();

    // ---- stage B + hidden layer, merged: thread (k = t>>4, q) redundantly
    //      computes s[q] (16 broadcast LDS reads) then hv[k][q]
    if (t < 256) {
        const int k = t >> 4;
        f32x4 s = (f32x4)(0.f);
        #pragma unroll
        for (int i = 0; i < 16; ++i) s += sA[i][q];
        s *= (1.0f / (float)NC);
        const float w1k = w1[k];
        const float b1k = b1[k];
        f32x4 hv;
        hv.x = fmaxf(fmaf(s.x, w1k, b1k), 0.f);
        hv.y = fmaxf(fmaf(s.y, w1k, b1k), 0.f);
        hv.z = fmaxf(fmaf(s.z, w1k, b1k), 0.f);
        hv.w = fmaxf(fmaf(s.w, w1k, b1k), 0.f);
        hv4[k][q] = hv;
    }
    __syncthreads();

    // ---- logits for 4 channels x quad, gate, store (256 FMA/thread)
    f32x4 acc[4];
    #pragma unroll
    for (int i = 0; i < 4; ++i) acc[i] = (f32x4)(b2s[(cg << 2) + i]);

    #pragma unroll
    for (int k = 0; k < NK; ++k) {
        const f32x4 hk = hv4[k][q];                                     // broadcast
        const f32x4 wv = *reinterpret_cast<const f32x4*>(&w2t[k][cg << 2]);
        acc[0] += hk * wv.x;
        acc[1] += hk * wv.y;
        acc[2] += hk * wv.z;
        acc[3] += hk * wv.w;
    }

    #pragma unroll
    for (int i = 0; i < 4; ++i) {
        const f32x4 xvv = xv[i];
        f32x4 r;
        r.x = xvv.x * fsig(acc[i].x);
        r.y = xvv.y * fsig(acc[i].y);
        r.z = xvv.z * fsig(acc[i].z);
        r.w = xvv.w * fsig(acc[i].w);
        __builtin_nontemporal_store(r,
            reinterpret_cast<f32x4*>(op + (size_t)((cg << 2) + i) * HW + (q << 2)));
    }
}

extern "C" void kernel_launch(void* const* d_in, const int* in_sizes, int n_in,
                              void* d_out, int out_size, void* d_ws, size_t ws_size,
                              hipStream_t stream) {
    const float* x  = (const float*)d_in[0];
    const float* w1 = (const float*)d_in[1];
    const float* b1 = (const float*)d_in[2];
    const float* w2 = (const float*)d_in[3];
    const float* b2 = (const float*)d_in[4];
    float* out = (float*)d_out;

    dim3 grid(NB * NH);   // 2048 blocks: one per (b, h) row
    dim3 block(1024);
    hipLaunchKernelGGL(pse_kernel, grid, block, 0, stream, x, w1, b1, w2, b2, out);
}